// Round 2
// baseline (262.802 us; speedup 1.0000x reference)
//
#include <hip/hip_runtime.h>
#include <hip/hip_bf16.h>

// R10: LDS-pipe theory. R9 post-mortem: compiler pinned VGPR=64 (won't hold
// full-layer weights); per-pair-per-layer LDS cost (6.1k cy reads + 3k cy
// scalar epilogue writes + conflicts) exceeds MFMA 5.5k cy -> LDS pipe is the
// busiest resource. Fix: transposed compute D[h][b] = W^T x H^T.
//  - A = weights (prepped layout reinterpreted, identical bytes)
//  - B = activations; 4 mg x 2 ng wave tiling halves LDS reads (16KB/wave/layer)
//  - C/D lanes hold 4 CONTIGUOUS h -> packed ds_write_b64 (32 scalar -> 8 b64)
//  - per-kb 4 independent L2 weight streams, 1-ahead prefetch (8 MFMA covers L2 hit)
//  - wave-local dtype sniff (no barrier, no LDS flag)
// Predict: bank-conflict 6.57M -> <1.5M, MfmaUtil 20.5 -> ~35%, fused 107 -> ~75us.

#define NB 65536
#define MROWS 64   // row tile (batch rows per block)
#define XSTR 296   // 592B row: 16B-unit stride 37 (odd) -> conflict-free b128
#define HSTR 264   // 528B row: 16B-unit stride 33 (odd) -> conflict-free b128

typedef __attribute__((ext_vector_type(8))) short short8;
typedef __attribute__((ext_vector_type(4))) short short4v;
typedef __attribute__((ext_vector_type(4))) float f32x4;
typedef __attribute__((ext_vector_type(2))) unsigned int uint2v;

__device__ __forceinline__ float bf2f(unsigned short u){
  union { unsigned int i; float f; } x; x.i = ((unsigned int)u) << 16; return x.f;
}
__device__ __forceinline__ unsigned short f2bf(float f){
  unsigned int x = __float_as_uint(f);
  x += 0x7fffu + ((x >> 16) & 1u);   // RNE
  return (unsigned short)(x >> 16);
}
__device__ __forceinline__ float ldval(const void* p, int idx, int isbf16){
  return isbf16 ? bf2f(((const unsigned short*)p)[idx]) : ((const float*)p)[idx];
}

// wave-local dtype sniff: every wave reads the SAME first 64 low-shorts of obs
// (L1-broadcast) and ballots on bf16-plausible exponents. No barrier needed.
__device__ __forceinline__ int wave_sniff(const void* obs, int lane){
  unsigned short u = ((const unsigned short*)obs)[lane * 2];
  int e = (u >> 7) & 0xFF;
  unsigned long long m = __ballot(e >= 110 && e <= 132);
  return (__popcll(m) >= 32) ? 1 : 0;
}

struct KParams {
  const void* obs;
  const void* act;
  const unsigned short* w1t[2];   // swizzled [task][g16][kb9][l16][quad][8]
  const unsigned short* w2t[2];   // swizzled [task][g16][kb8][l16][quad][8]
  const unsigned short* w3t[2];
  const void* b1[2];
  const void* b2[2];
  const void* b3[2];
  const void* w4[2];
  const void* b4[2];
  const int* counts;
  const int* perm;
  void* out;
};

// ---- routing task: exact input precision ----
__device__ __forceinline__ int task_of(const void* obs, int b, int isbf16){
  float v0, v1, v2;
  if (isbf16) {
    short4v u = *(const short4v*)((const unsigned short*)obs + b * 256 + 252);
    v0 = bf2f((unsigned short)u[1]); v1 = bf2f((unsigned short)u[2]); v2 = bf2f((unsigned short)u[3]);
  } else {
    f32x4 u = *(const f32x4*)((const float*)obs + b * 256 + 252);
    v0 = u[1]; v1 = u[2]; v2 = u[3];
  }
  int t = 0; float m = v0;
  if (v1 > m) { m = v1; t = 1; }   // strict > => first-occurrence argmax (jnp)
  if (v2 > m) { t = 2; }
  return t;
}

// ---- K1: blocks 0..599 = weight prep (swizzled frag layout; works as A or B
// operand since frag layouts are symmetric); blocks 600..855 = task histogram ----
__global__ void prep_count(const void* q1W1, const void* q1W2, const void* q1W3,
                           const void* q2W1, const void* q2W2, const void* q2W3,
                           const void* obs, unsigned short* out,
                           int* hist, unsigned char* tasks){
  int tid = threadIdx.x;
  int isbf16 = wave_sniff(obs, tid & 63);
  if (blockIdx.x >= 600) {             // ---- count role ----
    __shared__ int h[3];
    if (tid < 3) h[tid] = 0;
    __syncthreads();
    int blk = blockIdx.x - 600;
    int b = blk * 256 + tid;
    int t = task_of(obs, b, isbf16);
    tasks[b] = (unsigned char)t;
    atomicAdd(&h[t], 1);
    __syncthreads();
    if (tid < 3) hist[blk * 3 + tid] = h[tid];
    return;
  }
  // ---- prep role: thread writes 8 consecutive swizzled shorts ----
  int gid8 = (blockIdx.x * 256 + tid) * 8;
  int net = gid8 / 614400;
  int idx = gid8 - net * 614400;
  const void* W1 = net ? q2W1 : q1W1;
  const void* W2 = net ? q2W2 : q1W2;
  const void* W3 = net ? q2W3 : q1W3;
  short8 sv;
  if (idx < 221184) {                  // W1t: KC=9, per task 16*9*512=73728
    int t = idx / 73728; int i = idx - t * 73728;
    int g = i / 4608;  int r = i - g * 4608;
    int kb = r >> 9;   int q2 = r & 511;
    int l16 = q2 >> 5; int rem = q2 & 31;
    int n = g * 16 + l16;
    int k = kb * 32 + (rem & ~7);
    #pragma unroll
    for (int j = 0; j < 8; j++) {
      int kk = k + j;
      sv[j] = (kk < 264) ? (short)f2bf(ldval(W1, (t * 264 + kk) * 256 + n, isbf16)) : (short)0;
    }
  } else if (idx < 417792) {           // W2t: KC=8, per task 16*8*512=65536
    int j0 = idx - 221184;
    int t = j0 >> 16; int i = j0 & 65535;
    int g = i >> 12;  int r = i & 4095;
    int kb = r >> 9;  int q2 = r & 511;
    int l16 = q2 >> 5; int rem = q2 & 31;
    int n = g * 16 + l16;
    int k = kb * 32 + (rem & ~7);
    #pragma unroll
    for (int j = 0; j < 8; j++)
      sv[j] = (short)f2bf(ldval(W2, t * 65536 + (k + j) * 256 + n, isbf16));
  } else {                             // W3t
    int j0 = idx - 417792;
    int t = j0 >> 16; int i = j0 & 65535;
    int g = i >> 12;  int r = i & 4095;
    int kb = r >> 9;  int q2 = r & 511;
    int l16 = q2 >> 5; int rem = q2 & 31;
    int n = g * 16 + l16;
    int k = kb * 32 + (rem & ~7);
    #pragma unroll
    for (int j = 0; j < 8; j++)
      sv[j] = (short)f2bf(ldval(W3, t * 65536 + (k + j) * 256 + n, isbf16));
  }
  *(short8*)(out + net * 614400 + idx) = sv;
}

// ---- K2: scatter, atomic-free cross-block prefix from hists ----
__global__ void route_scatter(const unsigned char* __restrict__ tasks,
                              const int* __restrict__ hist,
                              int* counts, int* perm){
  __shared__ int sh[3][256];
  __shared__ int totals[3], pres[3], base[3], zz[3];
  int tid = threadIdx.x;
  int blk = blockIdx.x;
  sh[0][tid] = hist[tid * 3 + 0];
  sh[1][tid] = hist[tid * 3 + 1];
  sh[2][tid] = hist[tid * 3 + 2];
  if (tid < 3) zz[tid] = 0;
  __syncthreads();
  if (tid < 3) {
    int tot = 0, pre = 0;
    for (int b = 0; b < 256; b++) {
      int v = sh[tid][b];
      if (b < blk) pre += v;
      tot += v;
    }
    totals[tid] = tot; pres[tid] = pre;
  }
  __syncthreads();
  if (tid < 3) {
    int a0 = ((totals[0] + MROWS - 1) / MROWS) * MROWS;
    int a1 = ((totals[1] + MROWS - 1) / MROWS) * MROWS;
    int off = (tid == 0) ? 0 : (tid == 1) ? a0 : a0 + a1;
    base[tid] = off + pres[tid];
    if (blk == 0) counts[tid] = totals[tid];
  }
  __syncthreads();
  int b = blk * 256 + tid;
  int t = tasks[b];
  int r = atomicAdd(&zz[t], 1);
  perm[base[t] + r] = b;
}

// ---- transposed layer: D[h_out][b] = W^T x H^T ----
// wave(mg 0..3, ng 0..1): owns h_out [mg*64, mg*64+64) x batch [ng*32, ng*32+32)
// A = weights (4 m-tiles, global, 1-ahead prefetch); B = activations from LDS
// (2 n-tiles, ds_read_b128). Epilogue: lane holds 4 contiguous h -> ds_write_b64.
template<int KC>
__device__ __forceinline__ void run_layer_T(const unsigned short* __restrict__ lin, int lstride,
                                            const unsigned short* __restrict__ wt,
                                            const void* bias, unsigned short* __restrict__ lout,
                                            int isbf16, int mg, int ng, int quad, int l16){
  // bias per (tm, r): h = mg*64 + tm*16 + quad*4 + r  (hoisted, overlaps kb loop)
  float bv[4][4];
  #pragma unroll
  for (int tm = 0; tm < 4; tm++) {
    int hb = mg * 64 + tm * 16 + quad * 4;
    #pragma unroll
    for (int r = 0; r < 4; r++) bv[tm][r] = ldval(bias, hb + r, isbf16);
  }
  const unsigned short* wg[4];
  #pragma unroll
  for (int tm = 0; tm < 4; tm++)
    wg[tm] = wt + (mg * 4 + tm) * (KC * 512) + l16 * 32 + quad * 8;

  short8 a[4], an[4];
  #pragma unroll
  for (int tm = 0; tm < 4; tm++) a[tm] = *(const short8*)(wg[tm]);

  f32x4 acc[4][2];
  const f32x4 z = {0.f, 0.f, 0.f, 0.f};
  #pragma unroll
  for (int kb = 0; kb < KC; ++kb) {
    if (kb + 1 < KC) {
      #pragma unroll
      for (int tm = 0; tm < 4; tm++)
        an[tm] = *(const short8*)(wg[tm] + (kb + 1) * 512);
    }
    short8 bfr[2];
    #pragma unroll
    for (int tn = 0; tn < 2; tn++)
      bfr[tn] = *(const short8*)(lin + (ng * 32 + tn * 16 + l16) * lstride + kb * 32 + quad * 8);
    #pragma unroll
    for (int tm = 0; tm < 4; tm++)
      #pragma unroll
      for (int tn = 0; tn < 2; tn++)
        acc[tm][tn] = __builtin_amdgcn_mfma_f32_16x16x32_bf16(
            a[tm], bfr[tn], (kb == 0) ? z : acc[tm][tn], 0, 0, 0);
    if (kb + 1 < KC) {
      #pragma unroll
      for (int tm = 0; tm < 4; tm++) a[tm] = an[tm];
    }
  }
  // epilogue: C/D col=lane&15 -> batch, row=quad*4+r -> h (4 contiguous) -> b64
  #pragma unroll
  for (int tm = 0; tm < 4; tm++) {
    #pragma unroll
    for (int tn = 0; tn < 2; tn++) {
      f32x4 v = acc[tm][tn];
      unsigned int u0 = (unsigned int)f2bf(fmaxf(v[0] + bv[tm][0], 0.f))
                      | ((unsigned int)f2bf(fmaxf(v[1] + bv[tm][1], 0.f)) << 16);
      unsigned int u1 = (unsigned int)f2bf(fmaxf(v[2] + bv[tm][2], 0.f))
                      | ((unsigned int)f2bf(fmaxf(v[3] + bv[tm][3], 0.f)) << 16);
      uint2v w; w[0] = u0; w[1] = u1;
      *(uint2v*)(lout + (ng * 32 + tn * 16 + l16) * HSTR + mg * 64 + tm * 16 + quad * 4) = w;
    }
  }
}

// ---- fused: 64-row task-uniform tile, 512 thr / 8 waves; LDS 71,680B ->
// 2 blocks/CU = 16 waves/CU ----
__global__ __launch_bounds__(512, 4) void fused_kernel(KParams p){
  __shared__ unsigned short X[MROWS * XSTR];   // 37,888 B ; reused as HB after L1
  __shared__ unsigned short HA[MROWS * HSTR];  // 33,792 B  (total 71,680)
  unsigned short* HB = X;

  int tid = threadIdx.x;
  int net = blockIdx.y;
  int p0  = blockIdx.x * MROWS;
  int wave = tid >> 6, lane = tid & 63, quad = lane >> 4, l16 = lane & 15;
  int mg = wave & 3, ng = wave >> 2;

  int c0 = p.counts[0], c1 = p.counts[1], c2 = p.counts[2];
  int off1 = ((c0 + MROWS - 1) / MROWS) * MROWS;
  int off2 = off1 + ((c1 + MROWS - 1) / MROWS) * MROWS;
  int task  = (p0 >= off2) ? 2 : ((p0 >= off1) ? 1 : 0);
  int segend = (task == 0) ? c0 : (task == 1) ? off1 + c1 : off2 + c2;

  int isbf16 = wave_sniff(p.obs, lane);
  int bsz = isbf16 ? 2 : 4;

  // stage X: 8 threads/row (all 512 threads); validity is arithmetic
  {
    int srow = tid >> 3, seg = tid & 7;
    int pos = p0 + srow;
    int r = (pos < segend) ? p.perm[pos] : -1;
    #pragma unroll
    for (int j = 0; j < 5; ++j) {
      int c = seg + 8 * j;
      if (c <= 35) {
        short8 sv = {0,0,0,0,0,0,0,0};
        if (r >= 0 && c < 33) {
          if (isbf16) {
            const unsigned short* src = (c < 32) ? ((const unsigned short*)p.obs + r * 256 + c * 8)
                                                 : ((const unsigned short*)p.act + r * 8);
            sv = *(const short8*)src;
          } else {
            const float* src = (c < 32) ? ((const float*)p.obs + r * 256 + c * 8)
                                        : ((const float*)p.act + r * 8);
            f32x4 a = *(const f32x4*)src;
            f32x4 b = *(const f32x4*)(src + 4);
            #pragma unroll
            for (int q = 0; q < 4; q++) { sv[q] = (short)f2bf(a[q]); sv[4 + q] = (short)f2bf(b[q]); }
          }
        }
        *(short8*)(X + srow * XSTR + c * 8) = sv;
      }
    }
  }
  __syncthreads();

  // ---- L1 ----
  run_layer_T<9>(X, XSTR, p.w1t[net] + task * 73728,
                 (const char*)p.b1[net] + task * 256 * bsz, HA,
                 isbf16, mg, ng, quad, l16);
  __syncthreads();

  // ---- L2 ----
  run_layer_T<8>(HA, HSTR, p.w2t[net] + task * 65536,
                 (const char*)p.b2[net] + task * 256 * bsz, HB,
                 isbf16, mg, ng, quad, l16);
  __syncthreads();

  // ---- L3 ----
  run_layer_T<8>(HB, HSTR, p.w3t[net] + task * 65536,
                 (const char*)p.b3[net] + task * 256 * bsz, HA,
                 isbf16, mg, ng, quad, l16);

  // w4 slice + b4 prefetch: independent of LDS, latency drains under barrier
  int seg = tid & 7, row = tid >> 3;
  float wv[32];
  if (isbf16) {
    const unsigned short* w4p = (const unsigned short*)p.w4[net] + task * 256 + seg * 32;
    #pragma unroll
    for (int q = 0; q < 4; q++) {
      short8 t = *(const short8*)(w4p + q * 8);
      #pragma unroll
      for (int j = 0; j < 8; j++) wv[q * 8 + j] = bf2f((unsigned short)t[j]);
    }
  } else {
    const float* w4p = (const float*)p.w4[net] + task * 256 + seg * 32;
    #pragma unroll
    for (int q = 0; q < 8; q++) {
      f32x4 a = *(const f32x4*)(w4p + q * 4);
      #pragma unroll
      for (int j = 0; j < 4; j++) wv[q * 4 + j] = a[j];
    }
  }
  float b4v = ldval(p.b4[net], task, isbf16);
  __syncthreads();

  // ---- L4: y = h3 . w4 + b4  (8 threads/row, 3-level shuffle) ----
  {
    float s = 0.f;
    #pragma unroll
    for (int kk = 0; kk < 32; kk += 8) {
      short8 hv = *(const short8*)(HA + row * HSTR + seg * 32 + kk);
      #pragma unroll
      for (int j = 0; j < 8; j++)
        s += bf2f((unsigned short)hv[j]) * wv[kk + j];
    }
    s += __shfl_xor(s, 1);
    s += __shfl_xor(s, 2);
    s += __shfl_xor(s, 4);
    if (seg == 0) {
      int pos = p0 + row;
      if (pos < segend) {
        int r = p.perm[pos];
        float y = s + b4v;
        if (isbf16) ((unsigned short*)p.out)[net * NB + r] = f2bf(y);
        else        ((float*)p.out)[net * NB + r] = y;
      }
    }
  }
}

extern "C" void kernel_launch(void* const* d_in, const int* in_sizes, int n_in,
                              void* d_out, int out_size, void* d_ws, size_t ws_size,
                              hipStream_t stream) {
  char* ws = (char*)d_ws;
  int* counts  = (int*)ws;                                // 3 ints @0 (K2 stores)
  int* hist    = (int*)(ws + 64);                         // 256*3 ints (K1 stores)
  unsigned char* tasks = (unsigned char*)(ws + 3200);     // 65536 B (K1 stores)
  int* perm    = (int*)(ws + 68800);                      // <=65662 ints (K2 stores)
  unsigned short* wts  = (unsigned short*)(ws + 331520);  // 2*614400 bf16 (K1 stores)

  const void* obs = d_in[0];
  const void* act = d_in[1];

  prep_count<<<856, 256, 0, stream>>>(d_in[2], d_in[4], d_in[6],
                                      d_in[10], d_in[12], d_in[14],
                                      obs, wts, hist, tasks);
  route_scatter<<<256, 256, 0, stream>>>(tasks, hist, counts, perm);

  KParams kp;
  kp.obs = obs; kp.act = act;
  for (int q = 0; q < 2; q++) {
    int base = 2 + q * 8;
    kp.b1[q] = d_in[base + 1];
    kp.b2[q] = d_in[base + 3];
    kp.b3[q] = d_in[base + 5];
    kp.w4[q] = d_in[base + 6];
    kp.b4[q] = d_in[base + 7];
    kp.w1t[q] = wts + q * 614400;
    kp.w2t[q] = wts + q * 614400 + 221184;
    kp.w3t[q] = wts + q * 614400 + 417792;
  }
  kp.counts = counts; kp.perm = perm;
  kp.out = d_out;

  // 1026 tiles of 64 rows covers worst-case per-task padding (sum ceil <= 1026)
  fused_kernel<<<dim3(1026, 2), 512, 0, stream>>>(kp);
}

// Round 4
// 221.880 us; speedup vs baseline: 1.1844x; 1.1844x over previous
//
#include <hip/hip_runtime.h>
#include <hip/hip_bf16.h>

// R12 = R11 resubmit (round-3 bench was an infra failure: "container failed
// twice", no kernel verdict). Bounds/alignment/layout re-audited, no crash
// vector found. Theory unchanged from R11:
// R10 post-mortem: regression was the weight path (ng-dup doubled L2 weight
// traffic 24->48us/CU), NOT the transposed layout -- packed-b64 epilogue
// verified (-1.7M conflicts). R11 = R9 traffic profile (2 glob + 4 ds + 8
// MFMA per kb/wave, 1x weights) with waves splitting h (wave = 32 h x 64
// batch): A=W^T (same bytes), B=act. Read patterns byte-identical to R9;
// epilogue 8 ds_write_b64 vs 32 ds_write_b16.
// Predict: conflicts 6.57M->~4.2M, fused 107->~95, MfmaUtil ~23.

#define NB 65536
#define MROWS 64   // batch rows per block
#define XSTR 296   // 592B row: 16B-unit stride 37 (odd) -> conflict-free b128
#define HSTR 264   // 528B row: 16B-unit stride 33 (odd) -> conflict-free b128

typedef __attribute__((ext_vector_type(8))) short short8;
typedef __attribute__((ext_vector_type(4))) short short4v;
typedef __attribute__((ext_vector_type(4))) float f32x4;
typedef __attribute__((ext_vector_type(2))) unsigned int uint2v;

__device__ __forceinline__ float bf2f(unsigned short u){
  union { unsigned int i; float f; } x; x.i = ((unsigned int)u) << 16; return x.f;
}
__device__ __forceinline__ unsigned short f2bf(float f){
  unsigned int x = __float_as_uint(f);
  x += 0x7fffu + ((x >> 16) & 1u);   // RNE
  return (unsigned short)(x >> 16);
}
__device__ __forceinline__ float ldval(const void* p, int idx, int isbf16){
  return isbf16 ? bf2f(((const unsigned short*)p)[idx]) : ((const float*)p)[idx];
}

// wave-local dtype sniff: every wave reads the SAME first 64 low-shorts of obs
// (L1-broadcast) and ballots on bf16-plausible exponents. No barrier needed.
__device__ __forceinline__ int wave_sniff(const void* obs, int lane){
  unsigned short u = ((const unsigned short*)obs)[lane * 2];
  int e = (u >> 7) & 0xFF;
  unsigned long long m = __ballot(e >= 110 && e <= 132);
  return (__popcll(m) >= 32) ? 1 : 0;
}

struct KParams {
  const void* obs;
  const void* act;
  const unsigned short* w1t[2];   // swizzled [task][g16][kb9][l16][quad][8]
  const unsigned short* w2t[2];   // swizzled [task][g16][kb8][l16][quad][8]
  const unsigned short* w3t[2];
  const void* b1[2];
  const void* b2[2];
  const void* b3[2];
  const void* w4[2];
  const void* b4[2];
  const int* counts;
  const int* perm;
  void* out;
};

// ---- routing task: exact input precision ----
__device__ __forceinline__ int task_of(const void* obs, int b, int isbf16){
  float v0, v1, v2;
  if (isbf16) {
    short4v u = *(const short4v*)((const unsigned short*)obs + b * 256 + 252);
    v0 = bf2f((unsigned short)u[1]); v1 = bf2f((unsigned short)u[2]); v2 = bf2f((unsigned short)u[3]);
  } else {
    f32x4 u = *(const f32x4*)((const float*)obs + b * 256 + 252);
    v0 = u[1]; v1 = u[2]; v2 = u[3];
  }
  int t = 0; float m = v0;
  if (v1 > m) { m = v1; t = 1; }   // strict > => first-occurrence argmax (jnp)
  if (v2 > m) { t = 2; }
  return t;
}

// ---- K1: blocks 0..599 = weight prep (swizzled frag layout; bytes serve as
// A or B operand -- layouts symmetric); blocks 600..855 = task histogram ----
__global__ void prep_count(const void* q1W1, const void* q1W2, const void* q1W3,
                           const void* q2W1, const void* q2W2, const void* q2W3,
                           const void* obs, unsigned short* out,
                           int* hist, unsigned char* tasks){
  int tid = threadIdx.x;
  int isbf16 = wave_sniff(obs, tid & 63);
  if (blockIdx.x >= 600) {             // ---- count role ----
    __shared__ int h[3];
    if (tid < 3) h[tid] = 0;
    __syncthreads();
    int blk = blockIdx.x - 600;
    int b = blk * 256 + tid;
    int t = task_of(obs, b, isbf16);
    tasks[b] = (unsigned char)t;
    atomicAdd(&h[t], 1);
    __syncthreads();
    if (tid < 3) hist[blk * 3 + tid] = h[tid];
    return;
  }
  // ---- prep role: thread writes 8 consecutive swizzled shorts ----
  int gid8 = (blockIdx.x * 256 + tid) * 8;
  int net = gid8 / 614400;
  int idx = gid8 - net * 614400;
  const void* W1 = net ? q2W1 : q1W1;
  const void* W2 = net ? q2W2 : q1W2;
  const void* W3 = net ? q2W3 : q1W3;
  short8 sv;
  if (idx < 221184) {                  // W1t: KC=9, per task 16*9*512=73728
    int t = idx / 73728; int i = idx - t * 73728;
    int g = i / 4608;  int r = i - g * 4608;
    int kb = r >> 9;   int q2 = r & 511;
    int l16 = q2 >> 5; int rem = q2 & 31;
    int n = g * 16 + l16;
    int k = kb * 32 + (rem & ~7);
    #pragma unroll
    for (int j = 0; j < 8; j++) {
      int kk = k + j;
      sv[j] = (kk < 264) ? (short)f2bf(ldval(W1, (t * 264 + kk) * 256 + n, isbf16)) : (short)0;
    }
  } else if (idx < 417792) {           // W2t: KC=8, per task 16*8*512=65536
    int j0 = idx - 221184;
    int t = j0 >> 16; int i = j0 & 65535;
    int g = i >> 12;  int r = i & 4095;
    int kb = r >> 9;  int q2 = r & 511;
    int l16 = q2 >> 5; int rem = q2 & 31;
    int n = g * 16 + l16;
    int k = kb * 32 + (rem & ~7);
    #pragma unroll
    for (int j = 0; j < 8; j++)
      sv[j] = (short)f2bf(ldval(W2, t * 65536 + (k + j) * 256 + n, isbf16));
  } else {                             // W3t
    int j0 = idx - 417792;
    int t = j0 >> 16; int i = j0 & 65535;
    int g = i >> 12;  int r = i & 4095;
    int kb = r >> 9;  int q2 = r & 511;
    int l16 = q2 >> 5; int rem = q2 & 31;
    int n = g * 16 + l16;
    int k = kb * 32 + (rem & ~7);
    #pragma unroll
    for (int j = 0; j < 8; j++)
      sv[j] = (short)f2bf(ldval(W3, t * 65536 + (k + j) * 256 + n, isbf16));
  }
  *(short8*)(out + net * 614400 + idx) = sv;
}

// ---- K2: scatter, atomic-free cross-block prefix from hists ----
__global__ void route_scatter(const unsigned char* __restrict__ tasks,
                              const int* __restrict__ hist,
                              int* counts, int* perm){
  __shared__ int sh[3][256];
  __shared__ int totals[3], pres[3], base[3], zz[3];
  int tid = threadIdx.x;
  int blk = blockIdx.x;
  sh[0][tid] = hist[tid * 3 + 0];
  sh[1][tid] = hist[tid * 3 + 1];
  sh[2][tid] = hist[tid * 3 + 2];
  if (tid < 3) zz[tid] = 0;
  __syncthreads();
  if (tid < 3) {
    int tot = 0, pre = 0;
    for (int b = 0; b < 256; b++) {
      int v = sh[tid][b];
      if (b < blk) pre += v;
      tot += v;
    }
    totals[tid] = tot; pres[tid] = pre;
  }
  __syncthreads();
  if (tid < 3) {
    int a0 = ((totals[0] + MROWS - 1) / MROWS) * MROWS;
    int a1 = ((totals[1] + MROWS - 1) / MROWS) * MROWS;
    int off = (tid == 0) ? 0 : (tid == 1) ? a0 : a0 + a1;
    base[tid] = off + pres[tid];
    if (blk == 0) counts[tid] = totals[tid];
  }
  __syncthreads();
  int b = blk * 256 + tid;
  int t = tasks[b];
  int r = atomicAdd(&zz[t], 1);
  perm[base[t] + r] = b;
}

// ---- transposed layer: D[h][b] = W^T x H^T, wave mg owns h [mg*32, mg*32+32)
// x ALL 64 batch rows. Per kb: 2 coalesced global weight loads (A), 4 LDS
// b128 activation reads (B), 8 MFMA -- byte-identical traffic to R9.
// Epilogue: lane holds 4 contiguous h per tile -> 8 packed ds_write_b64. ----
template<int KC, int INSTR, int OUTSTR>
__device__ __forceinline__ void run_layer_T(const unsigned short* __restrict__ lin,
                                            const unsigned short* __restrict__ wt,
                                            const void* bias, unsigned short* __restrict__ lout,
                                            int isbf16, int mg, int quad, int l16){
  const unsigned short* wg0 = wt + (mg * 2 + 0) * (KC * 512) + l16 * 32 + quad * 8;
  const unsigned short* wg1 = wt + (mg * 2 + 1) * (KC * 512) + l16 * 32 + quad * 8;
  // bias per (tm, r): h = mg*32 + tm*16 + quad*4 + r (hoisted above kb loop)
  float bv[2][4];
  #pragma unroll
  for (int tm = 0; tm < 2; tm++)
    #pragma unroll
    for (int r = 0; r < 4; r++)
      bv[tm][r] = ldval(bias, mg * 32 + tm * 16 + quad * 4 + r, isbf16);

  f32x4 acc[2][4];
  const f32x4 z = {0.f, 0.f, 0.f, 0.f};
  #pragma unroll
  for (int kb = 0; kb < KC; ++kb) {
    short8 a0 = *(const short8*)(wg0 + kb * 512);
    short8 a1 = *(const short8*)(wg1 + kb * 512);
    short8 b[4];
    #pragma unroll
    for (int tn = 0; tn < 4; tn++)
      b[tn] = *(const short8*)(lin + (tn * 16 + l16) * INSTR + kb * 32 + quad * 8);
    #pragma unroll
    for (int tn = 0; tn < 4; tn++) {
      acc[0][tn] = __builtin_amdgcn_mfma_f32_16x16x32_bf16(a0, b[tn], (kb == 0) ? z : acc[0][tn], 0, 0, 0);
      acc[1][tn] = __builtin_amdgcn_mfma_f32_16x16x32_bf16(a1, b[tn], (kb == 0) ? z : acc[1][tn], 0, 0, 0);
    }
  }
  // epilogue: C/D col=lane&15 -> batch (tn*16+l16), row=quad*4+r -> h (4
  // contiguous at mg*32+tm*16+quad*4) -> one b64 per (tm,tn)
  #pragma unroll
  for (int tm = 0; tm < 2; tm++) {
    #pragma unroll
    for (int tn = 0; tn < 4; tn++) {
      f32x4 v = acc[tm][tn];
      unsigned int u0 = (unsigned int)f2bf(fmaxf(v[0] + bv[tm][0], 0.f))
                      | ((unsigned int)f2bf(fmaxf(v[1] + bv[tm][1], 0.f)) << 16);
      unsigned int u1 = (unsigned int)f2bf(fmaxf(v[2] + bv[tm][2], 0.f))
                      | ((unsigned int)f2bf(fmaxf(v[3] + bv[tm][3], 0.f)) << 16);
      uint2v w; w[0] = u0; w[1] = u1;
      *(uint2v*)(lout + (tn * 16 + l16) * OUTSTR + mg * 32 + tm * 16 + quad * 4) = w;
    }
  }
}

// ---- fused: 64-row task-uniform tile, 512 thr / 8 waves; LDS 71,680B ->
// 2 blocks/CU = 16 waves/CU ----
__global__ __launch_bounds__(512, 4) void fused_kernel(KParams p){
  __shared__ unsigned short X[MROWS * XSTR];   // 37,888 B ; reused as HB after L1
  __shared__ unsigned short HA[MROWS * HSTR];  // 33,792 B  (total 71,680)
  unsigned short* HB = X;

  int tid = threadIdx.x;
  int net = blockIdx.y;
  int p0  = blockIdx.x * MROWS;
  int wave = tid >> 6, lane = tid & 63, quad = lane >> 4, l16 = lane & 15;
  int mg = wave;   // wave owns h [mg*32, mg*32+32)

  int c0 = p.counts[0], c1 = p.counts[1], c2 = p.counts[2];
  int off1 = ((c0 + MROWS - 1) / MROWS) * MROWS;
  int off2 = off1 + ((c1 + MROWS - 1) / MROWS) * MROWS;
  int task  = (p0 >= off2) ? 2 : ((p0 >= off1) ? 1 : 0);
  int segend = (task == 0) ? c0 : (task == 1) ? off1 + c1 : off2 + c2;

  int isbf16 = wave_sniff(p.obs, lane);
  int bsz = isbf16 ? 2 : 4;

  // stage X: 8 threads/row (all 512 threads); validity is arithmetic
  {
    int srow = tid >> 3, seg = tid & 7;
    int pos = p0 + srow;
    int r = (pos < segend) ? p.perm[pos] : -1;
    #pragma unroll
    for (int j = 0; j < 5; ++j) {
      int c = seg + 8 * j;
      if (c <= 35) {
        short8 sv = {0,0,0,0,0,0,0,0};
        if (r >= 0 && c < 33) {
          if (isbf16) {
            const unsigned short* src = (c < 32) ? ((const unsigned short*)p.obs + r * 256 + c * 8)
                                                 : ((const unsigned short*)p.act + r * 8);
            sv = *(const short8*)src;
          } else {
            const float* src = (c < 32) ? ((const float*)p.obs + r * 256 + c * 8)
                                        : ((const float*)p.act + r * 8);
            f32x4 a = *(const f32x4*)src;
            f32x4 b = *(const f32x4*)(src + 4);
            #pragma unroll
            for (int q = 0; q < 4; q++) { sv[q] = (short)f2bf(a[q]); sv[4 + q] = (short)f2bf(b[q]); }
          }
        }
        *(short8*)(X + srow * XSTR + c * 8) = sv;
      }
    }
  }
  __syncthreads();

  // ---- L1 ----
  run_layer_T<9, XSTR, HSTR>(X, p.w1t[net] + task * 73728,
                             (const char*)p.b1[net] + task * 256 * bsz, HA,
                             isbf16, mg, quad, l16);
  __syncthreads();

  // ---- L2 ----
  run_layer_T<8, HSTR, XSTR>(HA, p.w2t[net] + task * 65536,
                             (const char*)p.b2[net] + task * 256 * bsz, HB,
                             isbf16, mg, quad, l16);
  __syncthreads();

  // ---- L3 ----
  run_layer_T<8, XSTR, HSTR>(HB, p.w3t[net] + task * 65536,
                             (const char*)p.b3[net] + task * 256 * bsz, HA,
                             isbf16, mg, quad, l16);

  // w4 slice + b4 prefetch: independent of LDS, latency drains under barrier
  int seg = tid & 7, row = tid >> 3;
  float wv[32];
  if (isbf16) {
    const unsigned short* w4p = (const unsigned short*)p.w4[net] + task * 256 + seg * 32;
    #pragma unroll
    for (int q = 0; q < 4; q++) {
      short8 t = *(const short8*)(w4p + q * 8);
      #pragma unroll
      for (int j = 0; j < 8; j++) wv[q * 8 + j] = bf2f((unsigned short)t[j]);
    }
  } else {
    const float* w4p = (const float*)p.w4[net] + task * 256 + seg * 32;
    #pragma unroll
    for (int q = 0; q < 8; q++) {
      f32x4 a = *(const f32x4*)(w4p + q * 4);
      #pragma unroll
      for (int j = 0; j < 4; j++) wv[q * 4 + j] = a[j];
    }
  }
  float b4v = ldval(p.b4[net], task, isbf16);
  __syncthreads();

  // ---- L4: y = h3 . w4 + b4  (8 threads/row, 3-level shuffle) ----
  {
    float s = 0.f;
    #pragma unroll
    for (int kk = 0; kk < 32; kk += 8) {
      short8 hv = *(const short8*)(HA + row * HSTR + seg * 32 + kk);
      #pragma unroll
      for (int j = 0; j < 8; j++)
        s += bf2f((unsigned short)hv[j]) * wv[kk + j];
    }
    s += __shfl_xor(s, 1);
    s += __shfl_xor(s, 2);
    s += __shfl_xor(s, 4);
    if (seg == 0) {
      int pos = p0 + row;
      if (pos < segend) {
        int r = p.perm[pos];
        float y = s + b4v;
        if (isbf16) ((unsigned short*)p.out)[net * NB + r] = f2bf(y);
        else        ((float*)p.out)[net * NB + r] = y;
      }
    }
  }
}

extern "C" void kernel_launch(void* const* d_in, const int* in_sizes, int n_in,
                              void* d_out, int out_size, void* d_ws, size_t ws_size,
                              hipStream_t stream) {
  char* ws = (char*)d_ws;
  int* counts  = (int*)ws;                                // 3 ints @0 (K2 stores)
  int* hist    = (int*)(ws + 64);                         // 256*3 ints (K1 stores)
  unsigned char* tasks = (unsigned char*)(ws + 3200);     // 65536 B (K1 stores)
  int* perm    = (int*)(ws + 68800);                      // <=65662 ints (K2 stores)
  unsigned short* wts  = (unsigned short*)(ws + 331520);  // 2*614400 bf16 (K1 stores)

  const void* obs = d_in[0];
  const void* act = d_in[1];

  prep_count<<<856, 256, 0, stream>>>(d_in[2], d_in[4], d_in[6],
                                      d_in[10], d_in[12], d_in[14],
                                      obs, wts, hist, tasks);
  route_scatter<<<256, 256, 0, stream>>>(tasks, hist, counts, perm);

  KParams kp;
  kp.obs = obs; kp.act = act;
  for (int q = 0; q < 2; q++) {
    int base = 2 + q * 8;
    kp.b1[q] = d_in[base + 1];
    kp.b2[q] = d_in[base + 3];
    kp.b3[q] = d_in[base + 5];
    kp.w4[q] = d_in[base + 6];
    kp.b4[q] = d_in[base + 7];
    kp.w1t[q] = wts + q * 614400;
    kp.w2t[q] = wts + q * 614400 + 221184;
    kp.w3t[q] = wts + q * 614400 + 417792;
  }
  kp.counts = counts; kp.perm = perm;
  kp.out = d_out;

  // 1026 tiles of 64 rows covers worst-case per-task padding (sum ceil <= 1026)
  fused_kernel<<<dim3(1026, 2), 512, 0, stream>>>(kp);
}